// Round 1
// baseline (998.045 us; speedup 1.0000x reference)
//
#include <hip/hip_runtime.h>
#include <math.h>

// ---------------- constants ----------------
#define D_MODEL   1024
#define MEM_SIZE  131072
#define TOP_K     64
#define D_STATE   16
#define D_CONV    4
#define D_INNER   2048
#define DT_RANK   64

// workspace byte offsets
#define WS_CAND1   0u          // u64[65536] (1024 blocks x 64)  = 524288 B
#define WS_CAND2   524288u     // u64[2048]                      = 16384 B
#define WS_IDXF    540672u     // int[64]
#define WS_U       540928u     // f32[64*2048]                   = 524288 B
#define WS_US      1065216u    // f32[64*2048]                   = 524288 B
#define WS_XDBL    1589504u    // f32[64*96]                     = 24576 B
#define WS_Z63     1614080u    // f32[2048]
#define WS_YFIN    1622272u    // f32[2048]
#define WS_CTX     1630464u    // f32[1024]

__device__ __forceinline__ float wave_reduce_add(float v) {
#pragma unroll
  for (int off = 32; off > 0; off >>= 1) v += __shfl_xor(v, off, 64);
  return v;
}

__device__ __forceinline__ unsigned long long pack_key(float sim, int idx) {
  unsigned int fb = __float_as_uint(sim);
  fb = (fb & 0x80000000u) ? ~fb : (fb | 0x80000000u);  // order-preserving map
  return ((unsigned long long)fb << 32) | (unsigned int)(~(unsigned int)idx);
}

// descending bitonic sort of N (pow2) u64 keys in LDS, 256 threads
template <int N>
__device__ __forceinline__ void bitonic_sort_desc(unsigned long long* keys, int tid) {
  for (int k = 2; k <= N; k <<= 1) {
    for (int j = k >> 1; j > 0; j >>= 1) {
      for (int i = tid; i < N; i += 256) {
        int ixj = i ^ j;
        if (ixj > i) {
          unsigned long long a = keys[i], b = keys[ixj];
          bool desc = ((i & k) == 0);
          if (desc ? (a < b) : (a > b)) { keys[i] = b; keys[ixj] = a; }
        }
      }
      __syncthreads();
    }
  }
}

// ---------------- K1: sims + per-block top-64 (+ fused usage copy) ----------------
// 1024 blocks x 256 thr -> 4 blocks/CU (16 waves/CU). 128 rows/block, 32 rows/wave.
// Plain cached float4 loads (nontemporal removed: bench the known-good 6.3 TB/s path).
__global__ __launch_bounds__(256) void k_sims(const float* __restrict__ mem,
                                              const float* __restrict__ query,
                                              const int* __restrict__ usage_in,
                                              float* __restrict__ usage_out,
                                              unsigned long long* __restrict__ cand1) {
  __shared__ float redq;
  __shared__ unsigned long long keys[128];
  const int tid = threadIdx.x, lane = tid & 63, wave = tid >> 6;

  // fused usage copy (int -> float), 128 elements per block
  if (tid < 128) {
    const int gi = blockIdx.x * 128 + tid;
    usage_out[gi] = (float)usage_in[gi];
  }

  const float4* q4 = (const float4*)query;
  const float4* m4 = (const float4*)mem;
  float4 qf[4];
  float qs = 0.f;
#pragma unroll
  for (int c = 0; c < 4; ++c) {
    qf[c] = q4[c * 64 + lane];
    qs += qf[c].x * qf[c].x + qf[c].y * qf[c].y + qf[c].z * qf[c].z + qf[c].w * qf[c].w;
  }
  qs = wave_reduce_add(qs);
  if (tid == 0) redq = qs;
  __syncthreads();
  const float qn = sqrtf(redq);

  const int base = blockIdx.x * 128 + wave * 32;  // 32 rows per wave
  for (int it = 0; it < 8; ++it) {
    const int r0 = base + it * 4;
    float d[4] = {0.f, 0.f, 0.f, 0.f}, s[4] = {0.f, 0.f, 0.f, 0.f};
#pragma unroll
    for (int c = 0; c < 4; ++c) {
#pragma unroll
      for (int k = 0; k < 4; ++k) {
        float4 a = m4[(size_t)(r0 + k) * 256 + c * 64 + lane];
        d[k] += a.x * qf[c].x + a.y * qf[c].y + a.z * qf[c].z + a.w * qf[c].w;
        s[k] += a.x * a.x + a.y * a.y + a.z * a.z + a.w * a.w;
      }
    }
#pragma unroll
    for (int k = 0; k < 4; ++k) {
      d[k] = wave_reduce_add(d[k]);
      s[k] = wave_reduce_add(s[k]);
    }
    if (lane == 0) {
#pragma unroll
      for (int k = 0; k < 4; ++k) {
        float sim = d[k] / fmaxf(sqrtf(s[k]) * qn, 1e-8f);
        keys[wave * 32 + it * 4 + k] = pack_key(sim, r0 + k);
      }
    }
  }
  __syncthreads();
  bitonic_sort_desc<128>(keys, tid);
  if (tid < 64) cand1[blockIdx.x * 64 + tid] = keys[tid];
}

// ---------------- K2: merge 65536 -> 2048 (32 blocks, 2048 keys each -> top 64) ----------------
__global__ __launch_bounds__(256) void k_merge2048(const unsigned long long* __restrict__ in,
                                                   unsigned long long* __restrict__ outk) {
  __shared__ unsigned long long keys[2048];
  const int tid = threadIdx.x;
  for (int i = tid; i < 2048; i += 256) keys[i] = in[blockIdx.x * 2048 + i];
  __syncthreads();
  bitonic_sort_desc<2048>(keys, tid);
  if (tid < 64) outk[blockIdx.x * 64 + tid] = keys[tid];
}

// ---------------- K3: final top-64 of 2048 + usage bump ----------------
__global__ __launch_bounds__(256) void k_final2048(const unsigned long long* __restrict__ in,
                                                   int* __restrict__ idxf,
                                                   float* __restrict__ usage_out) {
  __shared__ unsigned long long keys[2048];
  const int tid = threadIdx.x;
  for (int i = tid; i < 2048; i += 256) keys[i] = in[i];
  __syncthreads();
  bitonic_sort_desc<2048>(keys, tid);
  if (tid < 64) {
    unsigned int low = (unsigned int)(keys[tid] & 0xFFFFFFFFull);
    int idx = (int)(~low);
    idxf[tid] = idx;
    usage_out[idx] += 1.0f;
  }
}

// ---------------- K4: in_proj (u for all l; z only at l=63) ----------------
__global__ __launch_bounds__(256) void k_inproj(const float* __restrict__ mem,
                                                const float* __restrict__ inw,
                                                const int* __restrict__ idxf,
                                                float* __restrict__ u,
                                                float* __restrict__ z63) {
  const int tid = threadIdx.x, lane = tid & 63, wave = tid >> 6;
  const int bid = blockIdx.x;
  const float4* m4 = (const float4*)mem;
  const float4* w4 = (const float4*)inw;
  if (bid < 256) {
    const int e0 = bid * 8 + wave * 2;
    float4 wa[4], wb[4];
#pragma unroll
    for (int c = 0; c < 4; ++c) {
      wa[c] = w4[e0 * 256 + c * 64 + lane];
      wb[c] = w4[(e0 + 1) * 256 + c * 64 + lane];
    }
    for (int l = 0; l < 64; ++l) {
      const int r = idxf[l];
      float da = 0.f, db = 0.f;
#pragma unroll
      for (int c = 0; c < 4; ++c) {
        float4 x = m4[(size_t)r * 256 + c * 64 + lane];
        da += x.x * wa[c].x + x.y * wa[c].y + x.z * wa[c].z + x.w * wa[c].w;
        db += x.x * wb[c].x + x.y * wb[c].y + x.z * wb[c].z + x.w * wb[c].w;
      }
      da = wave_reduce_add(da);
      db = wave_reduce_add(db);
      if (lane == 0) {
        u[l * 2048 + e0]     = da;
        u[l * 2048 + e0 + 1] = db;
      }
    }
  } else {
    const int wid = (bid - 256) * 4 + wave;  // 0..127
    const int r63 = idxf[63];
    float4 xf[4];
#pragma unroll
    for (int c = 0; c < 4; ++c) xf[c] = m4[(size_t)r63 * 256 + c * 64 + lane];
    for (int j = 0; j < 16; ++j) {
      const int e = 2048 + wid * 16 + j;
      float dsum = 0.f;
#pragma unroll
      for (int c = 0; c < 4; ++c) {
        float4 w = w4[e * 256 + c * 64 + lane];
        dsum += w.x * xf[c].x + w.y * xf[c].y + w.z * xf[c].z + w.w * xf[c].w;
      }
      dsum = wave_reduce_add(dsum);
      if (lane == 0) z63[e - 2048] = dsum;
    }
  }
}

// ---------------- K5: conv(width4)+SiLU fused with x_proj ----------------
// grid = 64 (one block per token l). Conv result built directly in the LDS
// staging buffer x_proj consumes; also written to global 'us' for the scan.
__global__ __launch_bounds__(256) void k_xprojc(const float* __restrict__ u,
                                                const float* __restrict__ cw,
                                                const float* __restrict__ cb,
                                                const float* __restrict__ xw,
                                                float* __restrict__ us,
                                                float* __restrict__ xdbl) {
  __shared__ __align__(16) float su[2048];
  const int tid = threadIdx.x, lane = tid & 63, wave = tid >> 6;
  const int l = blockIdx.x;
  for (int i = tid; i < 2048; i += 256) {
    float acc = cb[i];
    const float4 w = ((const float4*)cw)[i];
    if (l >= 3) {
      acc += u[(l - 3) * 2048 + i] * w.x + u[(l - 2) * 2048 + i] * w.y +
             u[(l - 1) * 2048 + i] * w.z + u[l * 2048 + i] * w.w;
    } else {
      if (l - 3 + 1 >= 0) acc += u[(l - 2) * 2048 + i] * w.y;
      if (l - 3 + 2 >= 0) acc += u[(l - 1) * 2048 + i] * w.z;
      acc += u[l * 2048 + i] * w.w;
      if (l == 2) acc += u[0] * 0.f;  // no-op; l<3 cases handled above
      // explicit: for l=0 only w.w term; l=1 adds w.z; l=2 adds w.y (covered)
    }
    const float sv = acc / (1.f + __expf(-acc));
    su[i] = sv;
    us[l * 2048 + i] = sv;
  }
  __syncthreads();
  const float4* su4 = (const float4*)su;
  const float4* xw4 = (const float4*)xw;
  for (int j = wave; j < 96; j += 4) {
    float dsum = 0.f;
#pragma unroll
    for (int c = 0; c < 8; ++c) {
      float4 a = su4[c * 64 + lane];
      float4 w = xw4[j * 512 + c * 64 + lane];
      dsum += a.x * w.x + a.y * w.y + a.z * w.z + a.w * w.w;
    }
    dsum = wave_reduce_add(dsum);
    if (lane == 0) xdbl[l * 96 + j] = dsum;
  }
}

// ---------------- K6: dt_proj + softplus + selective scan (fused) ----------------
// grid = 128 blocks; block covers d in [bid*16, bid*16+16), all 16 states.
// delta computed in LDS (padded strides -> conflict-free), no global round-trip.
__global__ __launch_bounds__(256) void k_scanf(const float* __restrict__ xdbl,
                                               const float* __restrict__ dtw,
                                               const float* __restrict__ dtb,
                                               const float* __restrict__ us,
                                               const float* __restrict__ A_log,
                                               const float* __restrict__ Dp,
                                               const float* __restrict__ z63,
                                               float* __restrict__ yfin) {
  __shared__ float xl[64 * 97];   // xdbl [64][96] padded to stride 97
  __shared__ float wl[16 * 65];   // dt_proj_w rows for this block's 16 d's
  __shared__ float dl[64 * 17];   // delta [64][16] padded
  __shared__ float ul[64 * 17];   // us slice [64][16] padded
  const int tid = threadIdx.x;
  const int d0 = blockIdx.x * 16;

  for (int i = tid; i < 6144; i += 256) {
    const int l = i / 96, r = i - l * 96;
    xl[l * 97 + r] = xdbl[i];
  }
  for (int i = tid; i < 1024; i += 256) {
    const int dd = i >> 6, r = i & 63;
    wl[dd * 65 + r] = dtw[(d0 + dd) * 64 + r];
  }
  for (int i = tid; i < 1024; i += 256) {
    const int l = i >> 4, dd = i & 15;
    ul[l * 17 + dd] = us[l * 2048 + d0 + dd];
  }
  __syncthreads();

  // delta[l][dd] = softplus(dot(xdbl[l][:64], dtw[d0+dd]) + dtb)
  for (int i = tid; i < 1024; i += 256) {
    const int l = i >> 4, dd = i & 15;
    float acc = dtb[d0 + dd];
#pragma unroll
    for (int r = 0; r < 64; ++r) acc += xl[l * 97 + r] * wl[dd * 65 + r];
    dl[l * 17 + dd] = fmaxf(acc, 0.f) + log1pf(__expf(-fabsf(acc)));
  }
  __syncthreads();

  const int dd = tid >> 4, s = tid & 15;
  const int d = d0 + dd;
  const float A = -__expf(A_log[d * 16 + s]);
  float h = 0.f;
#pragma unroll 8
  for (int l = 0; l < 64; ++l) {
    const float dlv = dl[l * 17 + dd];
    const float bl  = xl[l * 97 + 64 + s];
    const float uv  = ul[l * 17 + dd];
    h = __expf(dlv * A) * h + dlv * bl * uv;
  }
  float v = h * xl[63 * 97 + 80 + s];
#pragma unroll
  for (int off = 8; off >= 1; off >>= 1) v += __shfl_xor(v, off, 64);
  if (s == 0) {
    const float y = v + ul[63 * 17 + dd] * Dp[d];
    const float z = z63[d];
    yfin[d] = y * (z / (1.f + __expf(-z)));
  }
}

// ---------------- K7: out_proj (only token 63) ----------------
__global__ __launch_bounds__(256) void k_outproj(const float* __restrict__ yfin,
                                                 const float* __restrict__ ow,
                                                 float* __restrict__ ctx) {
  const int tid = threadIdx.x, lane = tid & 63, wave = tid >> 6;
  const int m = blockIdx.x * 4 + wave;  // grid = 256
  const float4* y4 = (const float4*)yfin;
  const float4* ow4 = (const float4*)ow;
  float dsum = 0.f;
#pragma unroll
  for (int c = 0; c < 8; ++c) {
    float4 w = ow4[m * 512 + c * 64 + lane];
    float4 y = y4[c * 64 + lane];
    dsum += w.x * y.x + w.y * y.y + w.z * y.z + w.w * y.w;
  }
  dsum = wave_reduce_add(dsum);
  if (lane == 0) ctx[m] = dsum;
}

// ---------------- K8: LayerNorm ----------------
__global__ __launch_bounds__(256) void k_ln(const float* __restrict__ ctx,
                                            const float* __restrict__ g,
                                            const float* __restrict__ b,
                                            float* __restrict__ out) {
  __shared__ float red[8];
  const int tid = threadIdx.x, lane = tid & 63, wave = tid >> 6;
  float4 v = ((const float4*)ctx)[tid];
  float s1 = v.x + v.y + v.z + v.w;
  float s2 = v.x * v.x + v.y * v.y + v.z * v.z + v.w * v.w;
  s1 = wave_reduce_add(s1);
  s2 = wave_reduce_add(s2);
  if (lane == 0) { red[wave] = s1; red[4 + wave] = s2; }
  __syncthreads();
  const float mu = (red[0] + red[1] + red[2] + red[3]) * (1.f / 1024.f);
  const float var = (red[4] + red[5] + red[6] + red[7]) * (1.f / 1024.f) - mu * mu;
  const float rs = rsqrtf(var + 1e-5f);
  const int i0 = tid * 4;
  out[i0 + 0] = (v.x - mu) * rs * g[i0 + 0] + b[i0 + 0];
  out[i0 + 1] = (v.y - mu) * rs * g[i0 + 1] + b[i0 + 1];
  out[i0 + 2] = (v.z - mu) * rs * g[i0 + 2] + b[i0 + 2];
  out[i0 + 3] = (v.w - mu) * rs * g[i0 + 3] + b[i0 + 3];
}

extern "C" void kernel_launch(void* const* d_in, const int* in_sizes, int n_in,
                              void* d_out, int out_size, void* d_ws, size_t ws_size,
                              hipStream_t stream) {
  const float* query    = (const float*)d_in[0];
  const float* memory   = (const float*)d_in[1];
  const int*   usage_in = (const int*)d_in[2];
  const float* in_proj  = (const float*)d_in[3];
  const float* conv_w   = (const float*)d_in[4];
  const float* conv_b   = (const float*)d_in[5];
  const float* x_proj   = (const float*)d_in[6];
  const float* dt_proj  = (const float*)d_in[7];
  const float* dt_bias  = (const float*)d_in[8];
  const float* A_log    = (const float*)d_in[9];
  const float* Dp       = (const float*)d_in[10];
  const float* out_proj = (const float*)d_in[11];
  const float* ln_g     = (const float*)d_in[12];
  const float* ln_b     = (const float*)d_in[13];

  char* ws = (char*)d_ws;
  unsigned long long* cand1 = (unsigned long long*)(ws + WS_CAND1);
  unsigned long long* cand2 = (unsigned long long*)(ws + WS_CAND2);
  int*   idxf  = (int*)(ws + WS_IDXF);
  float* u     = (float*)(ws + WS_U);
  float* us_   = (float*)(ws + WS_US);
  float* xdbl  = (float*)(ws + WS_XDBL);
  float* z63   = (float*)(ws + WS_Z63);
  float* yfin  = (float*)(ws + WS_YFIN);
  float* ctx   = (float*)(ws + WS_CTX);

  float* out_ln    = (float*)d_out;         // 1024 floats
  float* usage_out = (float*)d_out + 1024;  // 131072 floats

  hipLaunchKernelGGL(k_sims,      dim3(1024), dim3(256), 0, stream, memory, query, usage_in, usage_out, cand1);
  hipLaunchKernelGGL(k_merge2048, dim3(32),   dim3(256), 0, stream, cand1, cand2);
  hipLaunchKernelGGL(k_final2048, dim3(1),    dim3(256), 0, stream, cand2, idxf, usage_out);
  hipLaunchKernelGGL(k_inproj,    dim3(288),  dim3(256), 0, stream, memory, in_proj, idxf, u, z63);
  hipLaunchKernelGGL(k_xprojc,    dim3(64),   dim3(256), 0, stream, u, conv_w, conv_b, x_proj, us_, xdbl);
  hipLaunchKernelGGL(k_scanf,     dim3(128),  dim3(256), 0, stream, xdbl, dt_proj, dt_bias, us_, A_log, Dp, z63, yfin);
  hipLaunchKernelGGL(k_outproj,   dim3(256),  dim3(256), 0, stream, yfin, out_proj, ctx);
  hipLaunchKernelGGL(k_ln,        dim3(1),    dim3(256), 0, stream, ctx, ln_g, ln_b, out_ln);
}

// Round 2
// 975.000 us; speedup vs baseline: 1.0236x; 1.0236x over previous
//
#include <hip/hip_runtime.h>
#include <math.h>

// ---------------- constants ----------------
#define D_MODEL   1024
#define MEM_SIZE  131072
#define TOP_K     64
#define D_STATE   16
#define D_CONV    4
#define D_INNER   2048
#define DT_RANK   64

// workspace byte offsets
#define WS_CAND1   0u          // u64[65536] (1024 blocks x 64)  = 524288 B
#define WS_CAND2   524288u     // u64[2048]                      = 16384 B
#define WS_IDXF    540672u     // int[64]
#define WS_U       540928u     // f32[64*2048]                   = 524288 B
#define WS_US      1065216u    // f32[64*2048]                   = 524288 B
#define WS_XDBL    1589504u    // f32[64*96]                     = 24576 B
#define WS_Z63     1614080u    // f32[2048]
#define WS_YFIN    1622272u    // f32[2048]
#define WS_CTX     1630464u    // f32[1024]

typedef float vfloat4 __attribute__((ext_vector_type(4)));

__device__ __forceinline__ float wave_reduce_add(float v) {
#pragma unroll
  for (int off = 32; off > 0; off >>= 1) v += __shfl_xor(v, off, 64);
  return v;
}

__device__ __forceinline__ vfloat4 ld_nt(const float* p) {
  return __builtin_nontemporal_load((const vfloat4*)p);
}

__device__ __forceinline__ unsigned long long pack_key(float sim, int idx) {
  unsigned int fb = __float_as_uint(sim);
  fb = (fb & 0x80000000u) ? ~fb : (fb | 0x80000000u);  // order-preserving map
  return ((unsigned long long)fb << 32) | (unsigned int)(~(unsigned int)idx);
}

// descending bitonic sort of N (pow2) u64 keys in LDS, 256 threads
template <int N>
__device__ __forceinline__ void bitonic_sort_desc(unsigned long long* keys, int tid) {
  for (int k = 2; k <= N; k <<= 1) {
    for (int j = k >> 1; j > 0; j >>= 1) {
      for (int i = tid; i < N; i += 256) {
        int ixj = i ^ j;
        if (ixj > i) {
          unsigned long long a = keys[i], b = keys[ixj];
          bool desc = ((i & k) == 0);
          if (desc ? (a < b) : (a > b)) { keys[i] = b; keys[ixj] = a; }
        }
      }
      __syncthreads();
    }
  }
}

// ---------------- K1: sims + per-block top-64 (+ fused usage copy) ----------------
// 1024 blocks x 256 thr -> 4 blocks/CU (16 waves/CU). 128 rows/block, 32 rows/wave.
// NONTEMPORAL loads restored: 512 MB stream is 2x L3, cached path thrashes (R0: +100us).
__global__ __launch_bounds__(256) void k_sims(const float* __restrict__ mem,
                                              const float* __restrict__ query,
                                              const int* __restrict__ usage_in,
                                              float* __restrict__ usage_out,
                                              unsigned long long* __restrict__ cand1) {
  __shared__ unsigned long long keys[128];
  const int tid = threadIdx.x, lane = tid & 63, wave = tid >> 6;

  // fused usage copy (int -> float), 128 elements per block
  if (tid < 128) {
    const int gi = blockIdx.x * 128 + tid;
    usage_out[gi] = (float)usage_in[gi];
  }

  const float4* q4 = (const float4*)query;
  float4 qf[4];
  float qs = 0.f;
#pragma unroll
  for (int c = 0; c < 4; ++c) {
    qf[c] = q4[c * 64 + lane];
    qs += qf[c].x * qf[c].x + qf[c].y * qf[c].y + qf[c].z * qf[c].z + qf[c].w * qf[c].w;
  }
  qs = wave_reduce_add(qs);           // every wave holds full ||q||^2 (64 lanes x 16 floats)
  const float qn = sqrtf(qs);         // no LDS round-trip / barrier needed

  const int base = blockIdx.x * 128 + wave * 32;  // 32 rows per wave
  for (int it = 0; it < 8; ++it) {
    const int r0 = base + it * 4;
    float d[4] = {0.f, 0.f, 0.f, 0.f}, s[4] = {0.f, 0.f, 0.f, 0.f};
#pragma unroll
    for (int c = 0; c < 4; ++c) {
#pragma unroll
      for (int k = 0; k < 4; ++k) {
        vfloat4 a = ld_nt(mem + (size_t)(r0 + k) * 1024 + c * 256 + lane * 4);
        d[k] += a.x * qf[c].x + a.y * qf[c].y + a.z * qf[c].z + a.w * qf[c].w;
        s[k] += a.x * a.x + a.y * a.y + a.z * a.z + a.w * a.w;
      }
    }
#pragma unroll
    for (int k = 0; k < 4; ++k) {
      d[k] = wave_reduce_add(d[k]);
      s[k] = wave_reduce_add(s[k]);
    }
    if (lane == 0) {
#pragma unroll
      for (int k = 0; k < 4; ++k) {
        float sim = d[k] / fmaxf(sqrtf(s[k]) * qn, 1e-8f);
        keys[wave * 32 + it * 4 + k] = pack_key(sim, r0 + k);
      }
    }
  }
  __syncthreads();
  bitonic_sort_desc<128>(keys, tid);
  if (tid < 64) cand1[blockIdx.x * 64 + tid] = keys[tid];
}

// ---------------- K2: merge 65536 -> 2048 (32 blocks, 2048 keys each -> top 64) ----------------
__global__ __launch_bounds__(256) void k_merge2048(const unsigned long long* __restrict__ in,
                                                   unsigned long long* __restrict__ outk) {
  __shared__ unsigned long long keys[2048];
  const int tid = threadIdx.x;
  for (int i = tid; i < 2048; i += 256) keys[i] = in[blockIdx.x * 2048 + i];
  __syncthreads();
  bitonic_sort_desc<2048>(keys, tid);
  if (tid < 64) outk[blockIdx.x * 64 + tid] = keys[tid];
}

// ---------------- K3: final top-64 of 2048 + usage bump ----------------
__global__ __launch_bounds__(256) void k_final2048(const unsigned long long* __restrict__ in,
                                                   int* __restrict__ idxf,
                                                   float* __restrict__ usage_out) {
  __shared__ unsigned long long keys[2048];
  const int tid = threadIdx.x;
  for (int i = tid; i < 2048; i += 256) keys[i] = in[i];
  __syncthreads();
  bitonic_sort_desc<2048>(keys, tid);
  if (tid < 64) {
    unsigned int low = (unsigned int)(keys[tid] & 0xFFFFFFFFull);
    int idx = (int)(~low);
    idxf[tid] = idx;
    usage_out[idx] += 1.0f;
  }
}

// ---------------- K4: in_proj (u for all l; z only at l=63) ----------------
__global__ __launch_bounds__(256) void k_inproj(const float* __restrict__ mem,
                                                const float* __restrict__ inw,
                                                const int* __restrict__ idxf,
                                                float* __restrict__ u,
                                                float* __restrict__ z63) {
  const int tid = threadIdx.x, lane = tid & 63, wave = tid >> 6;
  const int bid = blockIdx.x;
  const float4* m4 = (const float4*)mem;
  const float4* w4 = (const float4*)inw;
  if (bid < 256) {
    const int e0 = bid * 8 + wave * 2;
    float4 wa[4], wb[4];
#pragma unroll
    for (int c = 0; c < 4; ++c) {
      wa[c] = w4[e0 * 256 + c * 64 + lane];
      wb[c] = w4[(e0 + 1) * 256 + c * 64 + lane];
    }
    for (int l = 0; l < 64; ++l) {
      const int r = idxf[l];
      float da = 0.f, db = 0.f;
#pragma unroll
      for (int c = 0; c < 4; ++c) {
        float4 x = m4[(size_t)r * 256 + c * 64 + lane];
        da += x.x * wa[c].x + x.y * wa[c].y + x.z * wa[c].z + x.w * wa[c].w;
        db += x.x * wb[c].x + x.y * wb[c].y + x.z * wb[c].z + x.w * wb[c].w;
      }
      da = wave_reduce_add(da);
      db = wave_reduce_add(db);
      if (lane == 0) {
        u[l * 2048 + e0]     = da;
        u[l * 2048 + e0 + 1] = db;
      }
    }
  } else {
    const int wid = (bid - 256) * 4 + wave;  // 0..127
    const int r63 = idxf[63];
    float4 xf[4];
#pragma unroll
    for (int c = 0; c < 4; ++c) xf[c] = m4[(size_t)r63 * 256 + c * 64 + lane];
    for (int j = 0; j < 16; ++j) {
      const int e = 2048 + wid * 16 + j;
      float dsum = 0.f;
#pragma unroll
      for (int c = 0; c < 4; ++c) {
        float4 w = w4[e * 256 + c * 64 + lane];
        dsum += w.x * xf[c].x + w.y * xf[c].y + w.z * xf[c].z + w.w * xf[c].w;
      }
      dsum = wave_reduce_add(dsum);
      if (lane == 0) z63[e - 2048] = dsum;
    }
  }
}

// ---------------- K5: conv(width4)+SiLU fused with x_proj ----------------
__global__ __launch_bounds__(256) void k_xprojc(const float* __restrict__ u,
                                                const float* __restrict__ cw,
                                                const float* __restrict__ cb,
                                                const float* __restrict__ xw,
                                                float* __restrict__ us,
                                                float* __restrict__ xdbl) {
  __shared__ __align__(16) float su[2048];
  const int tid = threadIdx.x, lane = tid & 63, wave = tid >> 6;
  const int l = blockIdx.x;
  for (int i = tid; i < 2048; i += 256) {
    float acc = cb[i];
    const float4 w = ((const float4*)cw)[i];
    if (l >= 3) {
      acc += u[(l - 3) * 2048 + i] * w.x + u[(l - 2) * 2048 + i] * w.y +
             u[(l - 1) * 2048 + i] * w.z + u[l * 2048 + i] * w.w;
    } else {
      if (l >= 2) acc += u[(l - 2) * 2048 + i] * w.y;
      if (l >= 1) acc += u[(l - 1) * 2048 + i] * w.z;
      acc += u[l * 2048 + i] * w.w;
    }
    const float sv = acc / (1.f + __expf(-acc));
    su[i] = sv;
    us[l * 2048 + i] = sv;
  }
  __syncthreads();
  const float4* su4 = (const float4*)su;
  const float4* xw4 = (const float4*)xw;
  for (int j = wave; j < 96; j += 4) {
    float dsum = 0.f;
#pragma unroll
    for (int c = 0; c < 8; ++c) {
      float4 a = su4[c * 64 + lane];
      float4 w = xw4[j * 512 + c * 64 + lane];
      dsum += a.x * w.x + a.y * w.y + a.z * w.z + a.w * w.w;
    }
    dsum = wave_reduce_add(dsum);
    if (lane == 0) xdbl[l * 96 + j] = dsum;
  }
}

// ---------------- K6: dt_proj + softplus + selective scan (fused) ----------------
__global__ __launch_bounds__(256) void k_scanf(const float* __restrict__ xdbl,
                                               const float* __restrict__ dtw,
                                               const float* __restrict__ dtb,
                                               const float* __restrict__ us,
                                               const float* __restrict__ A_log,
                                               const float* __restrict__ Dp,
                                               const float* __restrict__ z63,
                                               float* __restrict__ yfin) {
  __shared__ float xl[64 * 97];   // xdbl [64][96] padded to stride 97
  __shared__ float wl[16 * 65];   // dt_proj_w rows for this block's 16 d's
  __shared__ float dl[64 * 17];   // delta [64][16] padded
  __shared__ float ul[64 * 17];   // us slice [64][16] padded
  const int tid = threadIdx.x;
  const int d0 = blockIdx.x * 16;

  for (int i = tid; i < 6144; i += 256) {
    const int l = i / 96, r = i - l * 96;
    xl[l * 97 + r] = xdbl[i];
  }
  for (int i = tid; i < 1024; i += 256) {
    const int dd = i >> 6, r = i & 63;
    wl[dd * 65 + r] = dtw[(d0 + dd) * 64 + r];
  }
  for (int i = tid; i < 1024; i += 256) {
    const int l = i >> 4, dd = i & 15;
    ul[l * 17 + dd] = us[l * 2048 + d0 + dd];
  }
  __syncthreads();

  for (int i = tid; i < 1024; i += 256) {
    const int l = i >> 4, dd = i & 15;
    float acc = dtb[d0 + dd];
#pragma unroll
    for (int r = 0; r < 64; ++r) acc += xl[l * 97 + r] * wl[dd * 65 + r];
    dl[l * 17 + dd] = fmaxf(acc, 0.f) + log1pf(__expf(-fabsf(acc)));
  }
  __syncthreads();

  const int dd = tid >> 4, s = tid & 15;
  const int d = d0 + dd;
  const float A = -__expf(A_log[d * 16 + s]);
  float h = 0.f;
#pragma unroll 8
  for (int l = 0; l < 64; ++l) {
    const float dlv = dl[l * 17 + dd];
    const float bl  = xl[l * 97 + 64 + s];
    const float uv  = ul[l * 17 + dd];
    h = __expf(dlv * A) * h + dlv * bl * uv;
  }
  float v = h * xl[63 * 97 + 80 + s];
#pragma unroll
  for (int off = 8; off >= 1; off >>= 1) v += __shfl_xor(v, off, 64);
  if (s == 0) {
    const float y = v + ul[63 * 17 + dd] * Dp[d];
    const float z = z63[d];
    yfin[d] = y * (z / (1.f + __expf(-z)));
  }
}

// ---------------- K7: out_proj (only token 63) ----------------
__global__ __launch_bounds__(256) void k_outproj(const float* __restrict__ yfin,
                                                 const float* __restrict__ ow,
                                                 float* __restrict__ ctx) {
  const int tid = threadIdx.x, lane = tid & 63, wave = tid >> 6;
  const int m = blockIdx.x * 4 + wave;  // grid = 256
  const float4* y4 = (const float4*)yfin;
  const float4* ow4 = (const float4*)ow;
  float dsum = 0.f;
#pragma unroll
  for (int c = 0; c < 8; ++c) {
    float4 w = ow4[m * 512 + c * 64 + lane];
    float4 y = y4[c * 64 + lane];
    dsum += w.x * y.x + w.y * y.y + w.z * y.z + w.w * y.w;
  }
  dsum = wave_reduce_add(dsum);
  if (lane == 0) ctx[m] = dsum;
}

// ---------------- K8: LayerNorm ----------------
__global__ __launch_bounds__(256) void k_ln(const float* __restrict__ ctx,
                                            const float* __restrict__ g,
                                            const float* __restrict__ b,
                                            float* __restrict__ out) {
  __shared__ float red[8];
  const int tid = threadIdx.x, lane = tid & 63, wave = tid >> 6;
  float4 v = ((const float4*)ctx)[tid];
  float s1 = v.x + v.y + v.z + v.w;
  float s2 = v.x * v.x + v.y * v.y + v.z * v.z + v.w * v.w;
  s1 = wave_reduce_add(s1);
  s2 = wave_reduce_add(s2);
  if (lane == 0) { red[wave] = s1; red[4 + wave] = s2; }
  __syncthreads();
  const float mu = (red[0] + red[1] + red[2] + red[3]) * (1.f / 1024.f);
  const float var = (red[4] + red[5] + red[6] + red[7]) * (1.f / 1024.f) - mu * mu;
  const float rs = rsqrtf(var + 1e-5f);
  const int i0 = tid * 4;
  out[i0 + 0] = (v.x - mu) * rs * g[i0 + 0] + b[i0 + 0];
  out[i0 + 1] = (v.y - mu) * rs * g[i0 + 1] + b[i0 + 1];
  out[i0 + 2] = (v.z - mu) * rs * g[i0 + 2] + b[i0 + 2];
  out[i0 + 3] = (v.w - mu) * rs * g[i0 + 3] + b[i0 + 3];
}

extern "C" void kernel_launch(void* const* d_in, const int* in_sizes, int n_in,
                              void* d_out, int out_size, void* d_ws, size_t ws_size,
                              hipStream_t stream) {
  const float* query    = (const float*)d_in[0];
  const float* memory   = (const float*)d_in[1];
  const int*   usage_in = (const int*)d_in[2];
  const float* in_proj  = (const float*)d_in[3];
  const float* conv_w   = (const float*)d_in[4];
  const float* conv_b   = (const float*)d_in[5];
  const float* x_proj   = (const float*)d_in[6];
  const float* dt_proj  = (const float*)d_in[7];
  const float* dt_bias  = (const float*)d_in[8];
  const float* A_log    = (const float*)d_in[9];
  const float* Dp       = (const float*)d_in[10];
  const float* out_proj = (const float*)d_in[11];
  const float* ln_g     = (const float*)d_in[12];
  const float* ln_b     = (const float*)d_in[13];

  char* ws = (char*)d_ws;
  unsigned long long* cand1 = (unsigned long long*)(ws + WS_CAND1);
  unsigned long long* cand2 = (unsigned long long*)(ws + WS_CAND2);
  int*   idxf  = (int*)(ws + WS_IDXF);
  float* u     = (float*)(ws + WS_U);
  float* us_   = (float*)(ws + WS_US);
  float* xdbl  = (float*)(ws + WS_XDBL);
  float* z63   = (float*)(ws + WS_Z63);
  float* yfin  = (float*)(ws + WS_YFIN);
  float* ctx   = (float*)(ws + WS_CTX);

  float* out_ln    = (float*)d_out;         // 1024 floats
  float* usage_out = (float*)d_out + 1024;  // 131072 floats

  hipLaunchKernelGGL(k_sims,      dim3(1024), dim3(256), 0, stream, memory, query, usage_in, usage_out, cand1);
  hipLaunchKernelGGL(k_merge2048, dim3(32),   dim3(256), 0, stream, cand1, cand2);
  hipLaunchKernelGGL(k_final2048, dim3(1),    dim3(256), 0, stream, cand2, idxf, usage_out);
  hipLaunchKernelGGL(k_inproj,    dim3(288),  dim3(256), 0, stream, memory, in_proj, idxf, u, z63);
  hipLaunchKernelGGL(k_xprojc,    dim3(64),   dim3(256), 0, stream, u, conv_w, conv_b, x_proj, us_, xdbl);
  hipLaunchKernelGGL(k_scanf,     dim3(128),  dim3(256), 0, stream, xdbl, dt_proj, dt_bias, us_, A_log, Dp, z63, yfin);
  hipLaunchKernelGGL(k_outproj,   dim3(256),  dim3(256), 0, stream, yfin, out_proj, ctx);
  hipLaunchKernelGGL(k_ln,        dim3(1),    dim3(256), 0, stream, ctx, ln_g, ln_b, out_ln);
}

// Round 3
// 898.155 us; speedup vs baseline: 1.1112x; 1.0856x over previous
//
#include <hip/hip_runtime.h>
#include <math.h>

// ---------------- constants ----------------
#define D_MODEL   1024
#define MEM_SIZE  131072
#define TOP_K     64
#define D_STATE   16
#define D_CONV    4
#define D_INNER   2048
#define DT_RANK   64

// workspace byte offsets (baseline layout)
#define WS_CAND1   0u          // u64[32768]  (512 blocks x 64)
#define WS_CAND2   262144u     // u64[2048]
#define WS_CAND3   278528u     // u64[128]
#define WS_IDXF    279552u     // int[64]
#define WS_U       294912u     // f32[64*2048]
#define WS_US      819200u     // f32[64*2048]
#define WS_XDBL    1343488u    // f32[64*96]
#define WS_Z63     1892352u    // f32[2048]
#define WS_YFIN    1900544u    // f32[2048]
#define WS_CTX     1908736u    // f32[1024]

typedef float vfloat4 __attribute__((ext_vector_type(4)));

__device__ __forceinline__ float wave_reduce_add(float v) {
#pragma unroll
  for (int off = 32; off > 0; off >>= 1) v += __shfl_xor(v, off, 64);
  return v;
}

__device__ __forceinline__ vfloat4 ld_nt(const float* p) {
  return __builtin_nontemporal_load((const vfloat4*)p);
}

__device__ __forceinline__ unsigned long long pack_key(float sim, int idx) {
  unsigned int fb = __float_as_uint(sim);
  fb = (fb & 0x80000000u) ? ~fb : (fb | 0x80000000u);  // order-preserving map
  return ((unsigned long long)fb << 32) | (unsigned int)(~(unsigned int)idx);
}

// descending bitonic sort of N (pow2) u64 keys in LDS, 256 threads
template <int N>
__device__ __forceinline__ void bitonic_sort_desc(unsigned long long* keys, int tid) {
  for (int k = 2; k <= N; k <<= 1) {
    for (int j = k >> 1; j > 0; j >>= 1) {
      for (int i = tid; i < N; i += 256) {
        int ixj = i ^ j;
        if (ixj > i) {
          unsigned long long a = keys[i], b = keys[ixj];
          bool desc = ((i & k) == 0);
          if (desc ? (a < b) : (a > b)) { keys[i] = b; keys[ixj] = a; }
        }
      }
      __syncthreads();
    }
  }
}

// ---------------- K1: sims + per-block top-64 (+ fused usage copy) ----------------
// BASELINE shape restored: 512 blocks x 256 thr; 64 rows/wave; NT loads.
// Only change vs baseline: q-norm reduced per-wave in registers (no LDS barrier).
__global__ __launch_bounds__(256) void k_sims(const float* __restrict__ mem,
                                              const float* __restrict__ query,
                                              const int* __restrict__ usage_in,
                                              float* __restrict__ usage_out,
                                              unsigned long long* __restrict__ cand1) {
  __shared__ unsigned long long keys[256];
  const int tid = threadIdx.x, lane = tid & 63, wave = tid >> 6;

  // fused usage copy (int -> float), one element per thread
  {
    const int gi = blockIdx.x * 256 + tid;
    usage_out[gi] = (float)usage_in[gi];
  }

  const float4* q4 = (const float4*)query;
  float4 qf[4];
  float qs = 0.f;
#pragma unroll
  for (int c = 0; c < 4; ++c) {
    qf[c] = q4[c * 64 + lane];
    qs += qf[c].x * qf[c].x + qf[c].y * qf[c].y + qf[c].z * qf[c].z + qf[c].w * qf[c].w;
  }
  qs = wave_reduce_add(qs);   // each wave holds full ||q||^2 (64 lanes x 16 floats)
  const float qn = sqrtf(qs);

  const int base = blockIdx.x * 256 + wave * 64;  // 64 rows per wave
  for (int it = 0; it < 16; ++it) {
    const int r0 = base + it * 4;
    float d[4] = {0.f, 0.f, 0.f, 0.f}, s[4] = {0.f, 0.f, 0.f, 0.f};
#pragma unroll
    for (int c = 0; c < 4; ++c) {
#pragma unroll
      for (int k = 0; k < 4; ++k) {
        vfloat4 a = ld_nt(mem + (size_t)(r0 + k) * 1024 + c * 256 + lane * 4);
        d[k] += a.x * qf[c].x + a.y * qf[c].y + a.z * qf[c].z + a.w * qf[c].w;
        s[k] += a.x * a.x + a.y * a.y + a.z * a.z + a.w * a.w;
      }
    }
#pragma unroll
    for (int k = 0; k < 4; ++k) {
      d[k] = wave_reduce_add(d[k]);
      s[k] = wave_reduce_add(s[k]);
    }
    if (lane == 0) {
#pragma unroll
      for (int k = 0; k < 4; ++k) {
        float sim = d[k] / fmaxf(sqrtf(s[k]) * qn, 1e-8f);
        keys[wave * 64 + it * 4 + k] = pack_key(sim, r0 + k);
      }
    }
  }
  __syncthreads();
  bitonic_sort_desc<256>(keys, tid);
  if (tid < 64) cand1[blockIdx.x * 64 + tid] = keys[tid];
}

// ---------------- K2: merge (1024 -> 64 per block); used twice ----------------
__global__ __launch_bounds__(256) void k_merge16(const unsigned long long* __restrict__ in,
                                                 unsigned long long* __restrict__ outk) {
  __shared__ unsigned long long keys[1024];
  const int tid = threadIdx.x;
  for (int i = tid; i < 1024; i += 256) keys[i] = in[blockIdx.x * 1024 + i];
  __syncthreads();
  bitonic_sort_desc<1024>(keys, tid);
  if (tid < 64) outk[blockIdx.x * 64 + tid] = keys[tid];
}

// ---------------- K3: final top-64 (of 128) + usage bump ----------------
__global__ __launch_bounds__(256) void k_final(const unsigned long long* __restrict__ in,
                                               int* __restrict__ idxf,
                                               float* __restrict__ usage_out) {
  __shared__ unsigned long long keys[128];
  const int tid = threadIdx.x;
  if (tid < 128) keys[tid] = in[tid];
  __syncthreads();
  bitonic_sort_desc<128>(keys, tid);
  if (tid < 64) {
    unsigned int low = (unsigned int)(keys[tid] & 0xFFFFFFFFull);
    int idx = (int)(~low);
    idxf[tid] = idx;
    usage_out[idx] += 1.0f;
  }
}

// ---------------- K4: in_proj (u for all l; z only at l=63) ----------------
__global__ __launch_bounds__(256) void k_inproj(const float* __restrict__ mem,
                                                const float* __restrict__ inw,
                                                const int* __restrict__ idxf,
                                                float* __restrict__ u,
                                                float* __restrict__ z63) {
  const int tid = threadIdx.x, lane = tid & 63, wave = tid >> 6;
  const int bid = blockIdx.x;
  const float4* m4 = (const float4*)mem;
  const float4* w4 = (const float4*)inw;
  if (bid < 256) {
    const int e0 = bid * 8 + wave * 2;
    float4 wa[4], wb[4];
#pragma unroll
    for (int c = 0; c < 4; ++c) {
      wa[c] = w4[e0 * 256 + c * 64 + lane];
      wb[c] = w4[(e0 + 1) * 256 + c * 64 + lane];
    }
    for (int l = 0; l < 64; ++l) {
      const int r = idxf[l];
      float da = 0.f, db = 0.f;
#pragma unroll
      for (int c = 0; c < 4; ++c) {
        float4 x = m4[(size_t)r * 256 + c * 64 + lane];
        da += x.x * wa[c].x + x.y * wa[c].y + x.z * wa[c].z + x.w * wa[c].w;
        db += x.x * wb[c].x + x.y * wb[c].y + x.z * wb[c].z + x.w * wb[c].w;
      }
      da = wave_reduce_add(da);
      db = wave_reduce_add(db);
      if (lane == 0) {
        u[l * 2048 + e0]     = da;
        u[l * 2048 + e0 + 1] = db;
      }
    }
  } else {
    const int wid = (bid - 256) * 4 + wave;  // 0..127
    const int r63 = idxf[63];
    float4 xf[4];
#pragma unroll
    for (int c = 0; c < 4; ++c) xf[c] = m4[(size_t)r63 * 256 + c * 64 + lane];
    for (int j = 0; j < 16; ++j) {
      const int e = 2048 + wid * 16 + j;
      float dsum = 0.f;
#pragma unroll
      for (int c = 0; c < 4; ++c) {
        float4 w = w4[e * 256 + c * 64 + lane];
        dsum += w.x * xf[c].x + w.y * xf[c].y + w.z * xf[c].z + w.w * xf[c].w;
      }
      dsum = wave_reduce_add(dsum);
      if (lane == 0) z63[e - 2048] = dsum;
    }
  }
}

// ---------------- K5: conv(width4)+SiLU fused with x_proj ----------------
__global__ __launch_bounds__(256) void k_xprojc(const float* __restrict__ u,
                                                const float* __restrict__ cw,
                                                const float* __restrict__ cb,
                                                const float* __restrict__ xw,
                                                float* __restrict__ us,
                                                float* __restrict__ xdbl) {
  __shared__ __align__(16) float su[2048];
  const int tid = threadIdx.x, lane = tid & 63, wave = tid >> 6;
  const int l = blockIdx.x;
  for (int i = tid; i < 2048; i += 256) {
    float acc = cb[i];
    const float4 w = ((const float4*)cw)[i];
    if (l >= 3) {
      acc += u[(l - 3) * 2048 + i] * w.x + u[(l - 2) * 2048 + i] * w.y +
             u[(l - 1) * 2048 + i] * w.z + u[l * 2048 + i] * w.w;
    } else {
      if (l >= 2) acc += u[(l - 2) * 2048 + i] * w.y;
      if (l >= 1) acc += u[(l - 1) * 2048 + i] * w.z;
      acc += u[l * 2048 + i] * w.w;
    }
    const float sv = acc / (1.f + __expf(-acc));
    su[i] = sv;
    us[l * 2048 + i] = sv;
  }
  __syncthreads();
  const float4* su4 = (const float4*)su;
  const float4* xw4 = (const float4*)xw;
  for (int j = wave; j < 96; j += 4) {
    float dsum = 0.f;
#pragma unroll
    for (int c = 0; c < 8; ++c) {
      float4 a = su4[c * 64 + lane];
      float4 w = xw4[j * 512 + c * 64 + lane];
      dsum += a.x * w.x + a.y * w.y + a.z * w.z + a.w * w.w;
    }
    dsum = wave_reduce_add(dsum);
    if (lane == 0) xdbl[l * 96 + j] = dsum;
  }
}

// ---------------- K6: dt_proj + softplus + selective scan (fused) ----------------
__global__ __launch_bounds__(256) void k_scanf(const float* __restrict__ xdbl,
                                               const float* __restrict__ dtw,
                                               const float* __restrict__ dtb,
                                               const float* __restrict__ us,
                                               const float* __restrict__ A_log,
                                               const float* __restrict__ Dp,
                                               const float* __restrict__ z63,
                                               float* __restrict__ yfin) {
  __shared__ float xl[64 * 97];   // xdbl [64][96] padded to stride 97
  __shared__ float wl[16 * 65];   // dt_proj_w rows for this block's 16 d's
  __shared__ float dl[64 * 17];   // delta [64][16] padded
  __shared__ float ul[64 * 17];   // us slice [64][16] padded
  const int tid = threadIdx.x;
  const int d0 = blockIdx.x * 16;

  for (int i = tid; i < 6144; i += 256) {
    const int l = i / 96, r = i - l * 96;
    xl[l * 97 + r] = xdbl[i];
  }
  for (int i = tid; i < 1024; i += 256) {
    const int dd = i >> 6, r = i & 63;
    wl[dd * 65 + r] = dtw[(d0 + dd) * 64 + r];
  }
  for (int i = tid; i < 1024; i += 256) {
    const int l = i >> 4, dd = i & 15;
    ul[l * 17 + dd] = us[l * 2048 + d0 + dd];
  }
  __syncthreads();

  for (int i = tid; i < 1024; i += 256) {
    const int l = i >> 4, dd = i & 15;
    float acc = dtb[d0 + dd];
#pragma unroll
    for (int r = 0; r < 64; ++r) acc += xl[l * 97 + r] * wl[dd * 65 + r];
    dl[l * 17 + dd] = fmaxf(acc, 0.f) + log1pf(__expf(-fabsf(acc)));
  }
  __syncthreads();

  const int dd = tid >> 4, s = tid & 15;
  const int d = d0 + dd;
  const float A = -__expf(A_log[d * 16 + s]);
  float h = 0.f;
#pragma unroll 8
  for (int l = 0; l < 64; ++l) {
    const float dlv = dl[l * 17 + dd];
    const float bl  = xl[l * 97 + 64 + s];
    const float uv  = ul[l * 17 + dd];
    h = __expf(dlv * A) * h + dlv * bl * uv;
  }
  float v = h * xl[63 * 97 + 80 + s];
#pragma unroll
  for (int off = 8; off >= 1; off >>= 1) v += __shfl_xor(v, off, 64);
  if (s == 0) {
    const float y = v + ul[63 * 17 + dd] * Dp[d];
    const float z = z63[d];
    yfin[d] = y * (z / (1.f + __expf(-z)));
  }
}

// ---------------- K7: out_proj (only token 63) ----------------
__global__ __launch_bounds__(256) void k_outproj(const float* __restrict__ yfin,
                                                 const float* __restrict__ ow,
                                                 float* __restrict__ ctx) {
  const int tid = threadIdx.x, lane = tid & 63, wave = tid >> 6;
  const int m = blockIdx.x * 4 + wave;  // grid = 256
  const float4* y4 = (const float4*)yfin;
  const float4* ow4 = (const float4*)ow;
  float dsum = 0.f;
#pragma unroll
  for (int c = 0; c < 8; ++c) {
    float4 w = ow4[m * 512 + c * 64 + lane];
    float4 y = y4[c * 64 + lane];
    dsum += w.x * y.x + w.y * y.y + w.z * y.z + w.w * y.w;
  }
  dsum = wave_reduce_add(dsum);
  if (lane == 0) ctx[m] = dsum;
}

// ---------------- K8: LayerNorm ----------------
__global__ __launch_bounds__(256) void k_ln(const float* __restrict__ ctx,
                                            const float* __restrict__ g,
                                            const float* __restrict__ b,
                                            float* __restrict__ out) {
  __shared__ float red[8];
  const int tid = threadIdx.x, lane = tid & 63, wave = tid >> 6;
  float4 v = ((const float4*)ctx)[tid];
  float s1 = v.x + v.y + v.z + v.w;
  float s2 = v.x * v.x + v.y * v.y + v.z * v.z + v.w * v.w;
  s1 = wave_reduce_add(s1);
  s2 = wave_reduce_add(s2);
  if (lane == 0) { red[wave] = s1; red[4 + wave] = s2; }
  __syncthreads();
  const float mu = (red[0] + red[1] + red[2] + red[3]) * (1.f / 1024.f);
  const float var = (red[4] + red[5] + red[6] + red[7]) * (1.f / 1024.f) - mu * mu;
  const float rs = rsqrtf(var + 1e-5f);
  const int i0 = tid * 4;
  out[i0 + 0] = (v.x - mu) * rs * g[i0 + 0] + b[i0 + 0];
  out[i0 + 1] = (v.y - mu) * rs * g[i0 + 1] + b[i0 + 1];
  out[i0 + 2] = (v.z - mu) * rs * g[i0 + 2] + b[i0 + 2];
  out[i0 + 3] = (v.w - mu) * rs * g[i0 + 3] + b[i0 + 3];
}

extern "C" void kernel_launch(void* const* d_in, const int* in_sizes, int n_in,
                              void* d_out, int out_size, void* d_ws, size_t ws_size,
                              hipStream_t stream) {
  const float* query    = (const float*)d_in[0];
  const float* memory   = (const float*)d_in[1];
  const int*   usage_in = (const int*)d_in[2];
  const float* in_proj  = (const float*)d_in[3];
  const float* conv_w   = (const float*)d_in[4];
  const float* conv_b   = (const float*)d_in[5];
  const float* x_proj   = (const float*)d_in[6];
  const float* dt_proj  = (const float*)d_in[7];
  const float* dt_bias  = (const float*)d_in[8];
  const float* A_log    = (const float*)d_in[9];
  const float* Dp       = (const float*)d_in[10];
  const float* out_proj = (const float*)d_in[11];
  const float* ln_g     = (const float*)d_in[12];
  const float* ln_b     = (const float*)d_in[13];

  char* ws = (char*)d_ws;
  unsigned long long* cand1 = (unsigned long long*)(ws + WS_CAND1);
  unsigned long long* cand2 = (unsigned long long*)(ws + WS_CAND2);
  unsigned long long* cand3 = (unsigned long long*)(ws + WS_CAND3);
  int*   idxf  = (int*)(ws + WS_IDXF);
  float* u     = (float*)(ws + WS_U);
  float* us_   = (float*)(ws + WS_US);
  float* xdbl  = (float*)(ws + WS_XDBL);
  float* z63   = (float*)(ws + WS_Z63);
  float* yfin  = (float*)(ws + WS_YFIN);
  float* ctx   = (float*)(ws + WS_CTX);

  float* out_ln    = (float*)d_out;         // 1024 floats
  float* usage_out = (float*)d_out + 1024;  // 131072 floats

  hipLaunchKernelGGL(k_sims,    dim3(512), dim3(256), 0, stream, memory, query, usage_in, usage_out, cand1);
  hipLaunchKernelGGL(k_merge16, dim3(32),  dim3(256), 0, stream, cand1, cand2);
  hipLaunchKernelGGL(k_merge16, dim3(2),   dim3(256), 0, stream, cand2, cand3);
  hipLaunchKernelGGL(k_final,   dim3(1),   dim3(256), 0, stream, cand3, idxf, usage_out);
  hipLaunchKernelGGL(k_inproj,  dim3(288), dim3(256), 0, stream, memory, in_proj, idxf, u, z63);
  hipLaunchKernelGGL(k_xprojc,  dim3(64),  dim3(256), 0, stream, u, conv_w, conv_b, x_proj, us_, xdbl);
  hipLaunchKernelGGL(k_scanf,   dim3(128), dim3(256), 0, stream, xdbl, dt_proj, dt_bias, us_, A_log, Dp, z63, yfin);
  hipLaunchKernelGGL(k_outproj, dim3(256), dim3(256), 0, stream, yfin, out_proj, ctx);
  hipLaunchKernelGGL(k_ln,      dim3(1),   dim3(256), 0, stream, ctx, ln_g, ln_b, out_ln);
}